// Round 13
// baseline (351.296 us; speedup 1.0000x reference)
//
#include <hip/hip_runtime.h>
#include <math.h>

typedef __attribute__((ext_vector_type(8))) short short8;
typedef __attribute__((ext_vector_type(4))) float f32x4;
typedef unsigned short ushort_t;

#define KVIN 15360   // 15069 padded; 960 = 15*64 per split (K%64==0)

__device__ __forceinline__ ushort_t f2bf(float f) {
  unsigned u = __float_as_uint(f);
  return (ushort_t)((u + 0x7fffu + ((u >> 16) & 1u)) >> 16);  // RNE
}
__device__ __forceinline__ float bf2f(ushort_t h) {
  return __uint_as_float(((unsigned)h) << 16);
}

// ---------------- block reduction helpers (256-thread blocks) ----------------
__device__ __forceinline__ float blockReduceSum256(float v, float* red) {
  #pragma unroll
  for (int o = 32; o; o >>= 1) v += __shfl_xor(v, o);
  int wid = threadIdx.x >> 6, lane = threadIdx.x & 63;
  if (lane == 0) red[wid] = v;
  __syncthreads();
  v = red[0] + red[1] + red[2] + red[3];
  __syncthreads();
  return v;
}
__device__ __forceinline__ float blockReduceMax256(float v, float* red) {
  #pragma unroll
  for (int o = 32; o; o >>= 1) v = fmaxf(v, __shfl_xor(v, o));
  int wid = threadIdx.x >> 6, lane = threadIdx.x & 63;
  if (lane == 0) red[wid] = v;
  __syncthreads();
  v = fmaxf(fmaxf(red[0], red[1]), fmaxf(red[2], red[3]));
  __syncthreads();
  return v;
}

// ===== 1-pass bf16 MFMA GEMM, 128x128 tile, BK=64, raw-barrier pipeline =====
// C = A @ B^T (+bias). A: bf16. B: bf16 (BF16B) or fp32 (converted in staging).
// N ragged (epilogue-guarded). K%64==0; kChunk%64==0.
// BIASM: 0 none, 1 +bias[gn], 2 +bias[gn]+biasB[gn].
// GMODE: 0 grid (nTile, mTile, z); 1 z-fastest; 2 XCD n-swizzle 1-D grid.
// ZDIV: 0 -> kBeg=z*kChunk, A/B offset z. >0 -> batch=z/ZDIV, ks=z%ZDIV; C offset z*cZ.
// LDS: 16B unit (row, q) q in 0..7 at unit-idx (row>>4)*128 + (q>>2)*64 + (q&3)*16
//   + (row&15) -> frag read for (row-block RB, k-half kk): units (RB*2+kk)*64 + lane
//   (= base + 16*lane bytes, conflict-free — layout family proven R6-R12, 0 conflicts).
// BK=64: 32 MFMA per k-step (2 kk-halves), HALF the barriers of BK=32 — amortizes the
// fixed per-step stage+wait+barrier overhead that R10-R12 proved schedule-invariant.
template <bool BF16B, int BIASM, bool CAUSAL, int GMODE, int ZDIV>
__global__ __launch_bounds__(256, 2) void glds6(
    const ushort_t* __restrict__ A, const void* __restrict__ Bv,
    const float* __restrict__ bias, const float* __restrict__ biasB,
    float* __restrict__ C,
    int N, int K, int lda, int ldb, int ldc,
    int kChunk, long aZ, long bZ, long cZ)
{
  int z, m0, n0;
  if (GMODE == 2) {
    const int id = blockIdx.x, u = id & 7, v = id >> 3;
    m0 = (v & 3) * 128;
    n0 = (((v >> 2) << 3) + u) * 128;
    z = 0;
    if (n0 >= N) return;
  } else if (GMODE == 1) {
    z = blockIdx.x; m0 = blockIdx.y * 128; n0 = blockIdx.z * 128;
  } else {
    z = blockIdx.z; m0 = blockIdx.y * 128; n0 = blockIdx.x * 128;
  }
  if (CAUSAL && n0 > m0 + 127) return;   // tile fully above diagonal (block-uniform)
  __shared__ ushort_t sA[2][8192], sB[2][8192];   // 2 bufs x 1024 units x 8 bf16 (64 KB)
  const int tid = threadIdx.x;
  const int ks = ZDIV ? (z % ZDIV) : z;
  const int zb = ZDIV ? (z / ZDIV) : z;
  const int kBeg = kChunk ? ks * kChunk : 0;
  const int kEnd = kChunk ? kBeg + kChunk : K;
  A += (size_t)zb * aZ;
  const ushort_t* Bh = (const ushort_t*)Bv;
  const float*    Bf = (const float*)Bv;
  if (BF16B) Bh += (size_t)zb * bZ; else Bf += (size_t)zb * bZ;
  C += (size_t)z * cZ;

  // staging map: thread t stages units {t, t+256, t+512, t+768}.
  // unit u -> RB=u>>7, kk=(u>>6)&1, q4=(u>>4)&3, rr=u&15; row=RB*16+rr, ko=kk*32+q4*8.
  // For thread t: rows ((t>>7)+2j)*16+(t&15) = base_row + 32j, ko fixed.
  const int brow = ((tid >> 7) << 4) | (tid & 15);          // 0..31
  const int ko   = (((tid >> 6) & 1) << 5) | (((tid >> 4) & 3) << 3);
  const ushort_t* pA0 = A + (size_t)(m0 + brow) * lda + ko;
  const ushort_t* pA1 = pA0 + (size_t)32 * lda;
  const ushort_t* pA2 = pA0 + (size_t)64 * lda;
  const ushort_t* pA3 = pA0 + (size_t)96 * lda;
  const int gn0 = n0 + brow, gn1 = gn0 + 32, gn2 = gn0 + 64, gn3 = gn0 + 96;
  const bool bok0 = gn0 < N, bok1 = gn1 < N, bok2 = gn2 < N, bok3 = gn3 < N;
  const ushort_t* pB0h = Bh + (size_t)gn0 * ldb + ko;
  const ushort_t* pB1h = Bh + (size_t)gn1 * ldb + ko;
  const ushort_t* pB2h = Bh + (size_t)gn2 * ldb + ko;
  const ushort_t* pB3h = Bh + (size_t)gn3 * ldb + ko;
  const float* pB0f = Bf + (size_t)gn0 * ldb + ko;
  const float* pB1f = Bf + (size_t)gn1 * ldb + ko;
  const float* pB2f = Bf + (size_t)gn2 * ldb + ko;
  const float* pB3f = Bf + (size_t)gn3 * ldb + ko;

  // waves 2x2, each 64x64
  const int lane = tid & 63;
  const int wrb = (tid >> 7) & 1;
  const int wcb = (tid >> 6) & 1;
  const int fr = lane & 15, fq = lane >> 4;

  f32x4 acc[4][4] = {};
  const short8 z8 = {0, 0, 0, 0, 0, 0, 0, 0};
  const float4 z4 = make_float4(0.f, 0.f, 0.f, 0.f);

  short8 ra0, ra1, ra2, ra3, rb0, rb1, rb2, rb3;
  float4 rf0, rf1, rf2, rf3, rf4, rf5, rf6, rf7;

#define LOADR(KK) {                                                                         \
  ra0 = *(const short8*)(pA0 + (KK)); ra1 = *(const short8*)(pA1 + (KK));                   \
  ra2 = *(const short8*)(pA2 + (KK)); ra3 = *(const short8*)(pA3 + (KK));                   \
  if (BF16B) {                                                                              \
    rb0 = bok0 ? *(const short8*)(pB0h + (KK)) : z8;                                        \
    rb1 = bok1 ? *(const short8*)(pB1h + (KK)) : z8;                                        \
    rb2 = bok2 ? *(const short8*)(pB2h + (KK)) : z8;                                        \
    rb3 = bok3 ? *(const short8*)(pB3h + (KK)) : z8;                                        \
  } else {                                                                                  \
    rf0 = bok0 ? *(const float4*)(pB0f + (KK)) : z4;                                        \
    rf1 = bok0 ? *(const float4*)(pB0f + (KK) + 4) : z4;                                    \
    rf2 = bok1 ? *(const float4*)(pB1f + (KK)) : z4;                                        \
    rf3 = bok1 ? *(const float4*)(pB1f + (KK) + 4) : z4;                                    \
    rf4 = bok2 ? *(const float4*)(pB2f + (KK)) : z4;                                        \
    rf5 = bok2 ? *(const float4*)(pB2f + (KK) + 4) : z4;                                    \
    rf6 = bok3 ? *(const float4*)(pB3f + (KK)) : z4;                                        \
    rf7 = bok3 ? *(const float4*)(pB3f + (KK) + 4) : z4;                                    \
  } }

#define STAGER(BUF) {                                                                       \
  *(short8*)&sA[BUF][tid << 3] = ra0;                                                       \
  *(short8*)&sA[BUF][(tid + 256) << 3] = ra1;                                               \
  *(short8*)&sA[BUF][(tid + 512) << 3] = ra2;                                               \
  *(short8*)&sA[BUF][(tid + 768) << 3] = ra3;                                               \
  if (BF16B) {                                                                              \
    *(short8*)&sB[BUF][tid << 3] = rb0;                                                     \
    *(short8*)&sB[BUF][(tid + 256) << 3] = rb1;                                             \
    *(short8*)&sB[BUF][(tid + 512) << 3] = rb2;                                             \
    *(short8*)&sB[BUF][(tid + 768) << 3] = rb3;                                             \
  } else {                                                                                  \
    short8 s0_, s1_, s2_, s3_;                                                              \
    _Pragma("unroll") for (int j = 0; j < 4; ++j) {                                         \
      s0_[j] = (short)f2bf(rf0[j]); s0_[j + 4] = (short)f2bf(rf1[j]);                       \
      s1_[j] = (short)f2bf(rf2[j]); s1_[j + 4] = (short)f2bf(rf3[j]);                       \
      s2_[j] = (short)f2bf(rf4[j]); s2_[j + 4] = (short)f2bf(rf5[j]);                       \
      s3_[j] = (short)f2bf(rf6[j]); s3_[j + 4] = (short)f2bf(rf7[j]); }                     \
    *(short8*)&sB[BUF][tid << 3] = s0_;                                                     \
    *(short8*)&sB[BUF][(tid + 256) << 3] = s1_;                                             \
    *(short8*)&sB[BUF][(tid + 512) << 3] = s2_;                                             \
    *(short8*)&sB[BUF][(tid + 768) << 3] = s3_;                                             \
  } }

// frag read for (RB = wrb*4+f, kk): ushort idx = ((RB*2+kk)*64 + lane) * 8
#define COMPUTE(BUF) {                                                                      \
  _Pragma("unroll") for (int kk = 0; kk < 2; ++kk) {                                        \
    short8 fa[4], fb[4];                                                                    \
    _Pragma("unroll") for (int f = 0; f < 4; ++f)                                           \
      fa[f] = *(const short8*)&sA[BUF][((((((wrb << 2) + f) << 1) + kk) << 6 | lane) << 3)];\
    _Pragma("unroll") for (int g = 0; g < 4; ++g)                                           \
      fb[g] = *(const short8*)&sB[BUF][((((((wcb << 2) + g) << 1) + kk) << 6 | lane) << 3)];\
    _Pragma("unroll") for (int f = 0; f < 4; ++f)                                           \
      _Pragma("unroll") for (int g = 0; g < 4; ++g)                                         \
        acc[f][g] = __builtin_amdgcn_mfma_f32_16x16x32_bf16(fa[f], fb[g], acc[f][g], 0,0,0);\
  } }

  LOADR(kBeg);
  const int nt = (kEnd - kBeg) >> 6;
  for (int t = 0; t < nt; ++t) {
    const int cur = t & 1;
    STAGER(cur);                                   // compiler waits vmcnt for R only
    if (t + 1 < nt) LOADR(kBeg + ((t + 1) << 6));  // in flight across the barrier
    asm volatile("s_waitcnt lgkmcnt(0)" ::: "memory");
    __builtin_amdgcn_s_barrier();                  // raw barrier: no vmcnt drain
    __builtin_amdgcn_sched_barrier(0);
    COMPUTE(cur);
    asm volatile("" ::: "memory");
  }

#undef LOADR
#undef STAGER
#undef COMPUTE

  // ---- epilogue: C/D layout col=lane&15, row=(lane>>4)*4+reg ----
  #pragma unroll
  for (int f = 0; f < 4; ++f) {
    const int gm = m0 + (wrb << 6) + f * 16 + fq * 4;
    #pragma unroll
    for (int g = 0; g < 4; ++g) {
      const int gn = n0 + (wcb << 6) + g * 16 + fr;
      if (gn < N) {
        #pragma unroll
        for (int i = 0; i < 4; ++i) {
          float v = acc[f][g][i];
          if (BIASM >= 1) v += bias[gn];
          if (BIASM >= 2) v += biasB[gn];
          C[(size_t)(gm + i) * ldc + gn] = v;
        }
      }
    }
  }
}

// ---------------- split-K combine: outh = bf16(sum_z part[z] + bias (+relu)) ----------------
template <bool RELU>
__global__ __launch_bounds__(256) void combine(
    const float* __restrict__ part, const float* __restrict__ bias,
    ushort_t* __restrict__ outh, int nz, long zstride, int total4, int N4)
{
  const int i = blockIdx.x * 256 + threadIdx.x;
  if (i >= total4) return;
  float4 s = ((const float4*)bias)[i % N4];
  for (int z = 0; z < nz; ++z) {
    float4 p = ((const float4*)(part + (size_t)z * zstride))[i];
    s.x += p.x; s.y += p.y; s.z += p.z; s.w += p.w;
  }
  if (RELU) {
    s.x = fmaxf(s.x, 0.f); s.y = fmaxf(s.y, 0.f);
    s.z = fmaxf(s.z, 0.f); s.w = fmaxf(s.w, 0.f);
  }
  ((ushort4*)outh)[i] = make_ushort4(f2bf(s.x), f2bf(s.y), f2bf(s.z), f2bf(s.w));
}

// PV combine: ctxh[t][h*256+d] = bf16(sum_{ks<4} pvpart[h*4+ks][t][d])
__global__ __launch_bounds__(256) void combine_pv(
    const float* __restrict__ part, ushort_t* __restrict__ ctxh)
{
  const int t = blockIdx.x, tid = threadIdx.x;
  const int h = tid >> 6, dq = tid & 63;
  float4 s = make_float4(0.f, 0.f, 0.f, 0.f);
  #pragma unroll
  for (int ks = 0; ks < 4; ++ks) {
    float4 p = ((const float4*)(part + (size_t)(h * 4 + ks) * 131072 + (size_t)t * 256))[dq];
    s.x += p.x; s.y += p.y; s.z += p.z; s.w += p.w;
  }
  ((ushort4*)ctxh)[t * 256 + h * 64 + dq] =
      make_ushort4(f2bf(s.x), f2bf(s.y), f2bf(s.z), f2bf(s.w));
}

// ---------------- fused split-K combine + residual + LayerNorm ----------------
__global__ __launch_bounds__(256) void ln_parts(
    const float* __restrict__ part, int nz, const float* __restrict__ bias,
    float* __restrict__ x, ushort_t* __restrict__ xh,
    const float* __restrict__ g, const float* __restrict__ b)
{
  const int t = blockIdx.x, tid = threadIdx.x;
  float4 y = ((const float4*)(x + (size_t)t * 1024))[tid];
  float4 s = ((const float4*)bias)[tid];
  for (int z = 0; z < nz; ++z) {
    float4 p = ((const float4*)(part + (size_t)z * 524288 + (size_t)t * 1024))[tid];
    s.x += p.x; s.y += p.y; s.z += p.z; s.w += p.w;
  }
  y.x += s.x; y.y += s.y; y.z += s.z; y.w += s.w;
  __shared__ float red[4];
  float sum = blockReduceSum256(y.x + y.y + y.z + y.w, red);
  const float m = sum * (1.f / 1024.f);
  float dx = y.x - m, dy = y.y - m, dz = y.z - m, dw = y.w - m;
  float q = blockReduceSum256(dx * dx + dy * dy + dz * dz + dw * dw, red);
  const float rs = rsqrtf(q * (1.f / 1024.f) + 1e-5f);
  float4 gg = ((const float4*)g)[tid], bb = ((const float4*)b)[tid];
  float4 o;
  o.x = dx * rs * gg.x + bb.x;
  o.y = dy * rs * gg.y + bb.y;
  o.z = dz * rs * gg.z + bb.z;
  o.w = dw * rs * gg.w + bb.w;
  ((float4*)(x + (size_t)t * 1024))[tid] = o;
  ((ushort4*)xh)[t * 256 + tid] = make_ushort4(f2bf(o.x), f2bf(o.y), f2bf(o.z), f2bf(o.w));
}

// ---------------- vectorized fp32 -> bf16 conversions ----------------
__global__ __launch_bounds__(256) void cvt_flat(
    const float* __restrict__ src, ushort_t* __restrict__ dst, int total4)
{
  const int i = blockIdx.x * 256 + threadIdx.x;
  if (i >= total4) return;
  float4 v = ((const float4*)src)[i];
  ((ushort4*)dst)[i] = make_ushort4(f2bf(v.x), f2bf(v.y), f2bf(v.z), f2bf(v.w));
}

__global__ __launch_bounds__(256) void cvt_pad(
    const float* __restrict__ src, ushort_t* __restrict__ dst,
    int Csrc, int Cdst4, int total4)
{
  const int i = blockIdx.x * 256 + threadIdx.x;
  if (i >= total4) return;
  const int r = i / Cdst4;
  const int c = (i - r * Cdst4) << 2;
  const float* s = src + (size_t)r * Csrc + c;
  ushort4 o = make_ushort4(0, 0, 0, 0);
  if (c + 3 < Csrc) {
    o = make_ushort4(f2bf(s[0]), f2bf(s[1]), f2bf(s[2]), f2bf(s[3]));
  } else {
    if (c + 0 < Csrc) o.x = f2bf(s[0]);
    if (c + 1 < Csrc) o.y = f2bf(s[1]);
    if (c + 2 < Csrc) o.z = f2bf(s[2]);
    if (c + 3 < Csrc) o.w = f2bf(s[3]);
  }
  ((ushort4*)dst)[i] = o;
}

__global__ __launch_bounds__(256) void prep_vin_v(
    const float* __restrict__ vertice, const float* __restrict__ tmpl,
    ushort_t* __restrict__ dst, int total4)
{
  const int i = blockIdx.x * 256 + threadIdx.x;
  if (i >= total4) return;
  const int C4 = KVIN >> 2;
  const int t = i / C4;
  const int c = (i - t * C4) << 2;
  ushort4 o = make_ushort4(0, 0, 0, 0);
  if (t > 0) {
    const float* s = vertice + (size_t)(t - 1) * 15069 + c;
    if (c + 3 < 15069) {
      o = make_ushort4(f2bf(s[0] - tmpl[c]),     f2bf(s[1] - tmpl[c + 1]),
                       f2bf(s[2] - tmpl[c + 2]), f2bf(s[3] - tmpl[c + 3]));
    } else {
      if (c + 0 < 15069) o.x = f2bf(s[0] - tmpl[c]);
      if (c + 1 < 15069) o.y = f2bf(s[1] - tmpl[c + 1]);
      if (c + 2 < 15069) o.z = f2bf(s[2] - tmpl[c + 2]);
      if (c + 3 < 15069) o.w = f2bf(s[3] - tmpl[c + 3]);
    }
  }
  ((ushort4*)dst)[i] = o;
}

// sum 16 vin split-K partials + (b_vm + style) + PE -> x (f32 + bf16)
__global__ __launch_bounds__(256) void reduce_pe(const float* __restrict__ part,
                                                 const float* __restrict__ one_hot,
                                                 const float* __restrict__ W_obj,
                                                 const float* __restrict__ b_vm,
                                                 float* __restrict__ x,
                                                 ushort_t* __restrict__ xh) {
  const int t = blockIdx.x;
  const float PECOEF = -9.210340371976184f / 512.f;  // -ln(10000)/512
  const int p = t % 25;
  for (int d = threadIdx.x; d < 1024; d += 256) {
    float s = b_vm[d];
    #pragma unroll
    for (int j = 0; j < 8; ++j) s += one_hot[j] * W_obj[d * 8 + j];
    #pragma unroll
    for (int z = 0; z < 16; ++z) s += part[(size_t)z * 524288 + (size_t)t * 1024 + d];
    float arg = (float)p * expf((float)(d >> 1) * PECOEF);
    s += (d & 1) ? cosf(arg) : sinf(arg);
    const size_t idx = (size_t)t * 1024 + d;
    x[idx] = s;
    xh[idx] = f2bf(s);
  }
}

// V transpose from qkv split-K parts: vth[d][s] = bf16(sum_z part[z][s][2048+d] + bias)
__global__ __launch_bounds__(256) void vT_parts(const float* __restrict__ part,
                                                const float* __restrict__ bias,
                                                ushort_t* __restrict__ vth) {
  __shared__ float tile[32][33];
  const int s0 = blockIdx.x * 32, d0 = blockIdx.y * 32;
  const int tx = threadIdx.x & 31, ty = threadIdx.x >> 5;  // 32 x 8
  for (int r = ty; r < 32; r += 8) {
    float v = bias[2048 + d0 + tx];
    #pragma unroll
    for (int z = 0; z < 4; ++z)
      v += part[(size_t)z * 1572864 + (size_t)(s0 + r) * 3072 + 2048 + d0 + tx];
    tile[r][tx] = v;
  }
  __syncthreads();
  for (int r = ty; r < 32; r += 8)
    vth[(size_t)(d0 + r) * 512 + s0 + tx] = f2bf(tile[tx][r]);
}

// row softmax with ALIBI + causal; reads TWO fp32 score partials per head, writes attn bf16
__global__ __launch_bounds__(256) void softmax_alibi(const float* __restrict__ scores,
                                                     ushort_t* __restrict__ ah) {
  const int i = blockIdx.x, h = blockIdx.y;
  const float* r0 = scores + (size_t)(2 * h) * 262144 + (size_t)i * 512;
  const float* r1 = r0 + 262144;
  const size_t rb = ((size_t)h * 512 + i) * 512;
  const int tid = threadIdx.x;
  const int len = i + 1;
  const float sl = exp2f(-2.f * (float)(h + 1));
  const int j0 = tid, j1 = tid + 256;
  float v0 = -INFINITY, v1 = -INFINITY;
  if (j0 < len) v0 = (r0[j0] + r1[j0]) * 0.0625f - sl * (float)((i - j0) / 25);
  if (j1 < len) v1 = (r0[j1] + r1[j1]) * 0.0625f - sl * (float)((i - j1) / 25);
  __shared__ float red[4];
  float m = blockReduceMax256(fmaxf(v0, v1), red);
  float e0 = (j0 < len) ? expf(v0 - m) : 0.f;
  float e1 = (j1 < len) ? expf(v1 - m) : 0.f;
  float s = blockReduceSum256(e0 + e1, red);
  float inv = 1.f / s;
  ah[rb + j0] = f2bf(e0 * inv);
  ah[rb + j1] = f2bf(e1 * inv);
}

// ---------------- host-side launch ----------------
extern "C" void kernel_launch(void* const* d_in, const int* in_sizes, int n_in,
                              void* d_out, int out_size, void* d_ws, size_t ws_size,
                              hipStream_t stream) {
  const float* audio   = (const float*)d_in[0];
  const float* vertice = (const float*)d_in[1];
  const float* tmpl    = (const float*)d_in[2];
  const float* one_hot = (const float*)d_in[3];
  const float* W_af    = (const float*)d_in[4];
  const float* b_af    = (const float*)d_in[5];
  const float* W_vm    = (const float*)d_in[6];
  const float* b_vm    = (const float*)d_in[7];
  const float* W_obj   = (const float*)d_in[8];
  const float* Wqkv_sa = (const float*)d_in[9];
  const float* bqkv_sa = (const float*)d_in[10];
  const float* Wo_sa   = (const float*)d_in[11];
  const float* bo_sa   = (const float*)d_in[12];
  const float* Wqkv_ca = (const float*)d_in[13];
  const float* bqkv_ca = (const float*)d_in[14];
  const float* Wo_ca   = (const float*)d_in[15];
  const float* bo_ca   = (const float*)d_in[16];
  const float* W1      = (const float*)d_in[17];
  const float* b1      = (const float*)d_in[18];
  const float* W2      = (const float*)d_in[19];
  const float* b2      = (const float*)d_in[20];
  const float* g1      = (const float*)d_in[21];
  const float* be1     = (const float*)d_in[22];
  const float* g2      = (const float*)d_in[23];
  const float* be2     = (const float*)d_in[24];
  const float* g3      = (const float*)d_in[25];
  const float* be3     = (const float*)d_in[26];
  const float* W_vr    = (const float*)d_in[27];
  const float* b_vr    = (const float*)d_in[28];
  float* out = (float*)d_out;

  // ---- workspace carve (floats), total ~113 MB ----
  float* base = (float*)d_ws;
  float* apF    = base;                  // 512*15360 us  = 3,932,160 fl
  float* wvmF   = apF + 3932160;         // 1024*15360 us = 7,864,320 fl (Wvm, then Wvr after vin)
  float* part   = wvmF + 7864320;        // 16*524288     = 8,388,608 fl
  float* x      = part + 8388608;        // 524,288
  float* xhF    = x + 524288;            // 262,144 (512*1024 us)
  float* audF   = xhF + 262144;          // 196,608 (512*768 us)
  float* hidF   = audF + 196608;         // 262,144
  float* qkvF   = hidF + 262144;         // 786,432 (512*3072 us)
  float* vtF    = qkvF + 786432;         // 262,144 (1024*512 us)
  float* scores = vtF + 262144;          // 2,097,152 (8 x 512x512 fp32 partials)
  float* attF   = scores + 2097152;      // 524,288 (4*512*512 us)
  float* pvpart = attF + 524288;         // 2,097,152 (16 x 512x256 fp32 partials)
  float* ctxF   = pvpart + 2097152;      // 262,144
  float* cvF    = ctxF + 262144;         // 262,144
  float* h1F    = cvF + 262144;          // 524,288 (512*2048 us)

  ushort_t* Aph  = (ushort_t*)apF;
  ushort_t* Wvmh = (ushort_t*)wvmF;
  ushort_t* Wvrh = (ushort_t*)wvmF;      // alias: Wvm dead after vin GEMM
  ushort_t* xh   = (ushort_t*)xhF;
  ushort_t* audh = (ushort_t*)audF;
  ushort_t* hidh = (ushort_t*)hidF;
  ushort_t* qkvh = (ushort_t*)qkvF;
  ushort_t* vth  = (ushort_t*)vtF;
  ushort_t* atth = (ushort_t*)attF;
  ushort_t* ctxh = (ushort_t*)ctxF;
  ushort_t* cvh  = (ushort_t*)cvF;
  ushort_t* h1h  = (ushort_t*)h1F;

  // ---- prep (all vectorized) ----
  prep_vin_v<<<7680, 256, 0, stream>>>(vertice, tmpl, Aph, 512 * (KVIN / 4));
  cvt_pad<<<15360, 256, 0, stream>>>(W_vm, Wvmh, 15069, KVIN / 4, 1024 * (KVIN / 4));

  // ---- vin = Ap @ Wvm^T  (split-K x16, z-fastest for XCD/L2 locality) ----
  glds6<true, 0, false, 1, 0><<<dim3(16, 4, 8), 256, 0, stream>>>(
      Aph, Wvmh, nullptr, nullptr, part,
      1024, KVIN, KVIN, KVIN, 1024, 960, 0, 0, 524288);
  reduce_pe<<<512, 256, 0, stream>>>(part, one_hot, W_obj, b_vm, x, xh);

  // Wvr bf16 (reuse wvm region; Wvm dead after vin GEMM above)
  cvt_flat<<<15069, 256, 0, stream>>>(W_vr, Wvrh, 15069 * 256);

  // ---- hidden = audio @ W_af^T + b_af ----
  cvt_flat<<<384, 256, 0, stream>>>(audio, audh, 512 * 192);
  glds6<false, 0, false, 0, 0><<<dim3(8, 4, 6), 256, 0, stream>>>(
      audh, W_af, nullptr, nullptr, part,
      1024, 768, 768, 768, 1024, 128, 0, 0, 524288);
  combine<false><<<512, 256, 0, stream>>>(part, b_af, hidh, 6, 524288, 131072, 256);

  // ---- self attention ----
  glds6<false, 0, false, 0, 0><<<dim3(24, 4, 4), 256, 0, stream>>>(
      xh, Wqkv_sa, nullptr, nullptr, part,
      3072, 1024, 1024, 1024, 3072, 256, 0, 0, 1572864);
  combine<false><<<1536, 256, 0, stream>>>(part, bqkv_sa, qkvh, 4, 1572864, 393216, 768);
  vT_parts<<<dim3(16, 32), 256, 0, stream>>>(part, bqkv_sa, vth);
  // scores partials: z = head*2 + ks (kChunk=128 selects head cols automatically)
  glds6<true, 0, true, 0, 0><<<dim3(4, 4, 8), 256, 0, stream>>>(
      qkvh, qkvh + 1024, nullptr, nullptr, scores,
      512, 1024, 3072, 3072, 512, 128, 0, 0, 262144);
  softmax_alibi<<<dim3(512, 4), 256, 0, stream>>>(scores, atth);
  // ctx partials: z = head*4 + ks (ZDIV=4), fp32 partials -> combine_pv
  glds6<true, 0, false, 0, 4><<<dim3(2, 4, 16), 256, 0, stream>>>(
      atth, vth, nullptr, nullptr, pvpart,
      256, 512, 512, 512, 256, 128, 262144, 131072, 131072);
  combine_pv<<<512, 256, 0, stream>>>(pvpart, ctxh);
  // out proj + LN
  glds6<false, 0, false, 0, 0><<<dim3(8, 4, 8), 256, 0, stream>>>(
      ctxh, Wo_sa, nullptr, nullptr, part,
      1024, 1024, 1024, 1024, 1024, 128, 0, 0, 524288);
  ln_parts<<<512, 256, 0, stream>>>(part, 8, bo_sa, x, xh, g1, be1);

  // ---- cross attention: bool mask == identity -> V then O projection ----
  glds6<false, 0, false, 0, 0><<<dim3(8, 4, 8), 256, 0, stream>>>(
      hidh, Wqkv_ca + (size_t)2048 * 1024, nullptr, nullptr, part,
      1024, 1024, 1024, 1024, 1024, 128, 0, 0, 524288);
  combine<false><<<512, 256, 0, stream>>>(part, bqkv_ca + 2048, cvh, 8, 524288, 131072, 256);
  glds6<false, 0, false, 0, 0><<<dim3(8, 4, 8), 256, 0, stream>>>(
      cvh, Wo_ca, nullptr, nullptr, part,
      1024, 1024, 1024, 1024, 1024, 128, 0, 0, 524288);
  ln_parts<<<512, 256, 0, stream>>>(part, 8, bo_ca, x, xh, g2, be2);

  // ---- feed forward ----
  glds6<false, 0, false, 0, 0><<<dim3(16, 4, 4), 256, 0, stream>>>(
      xh, W1, nullptr, nullptr, part,
      2048, 1024, 1024, 1024, 2048, 256, 0, 0, 1048576);
  combine<true><<<1024, 256, 0, stream>>>(part, b1, h1h, 4, 1048576, 262144, 512);
  glds6<false, 0, false, 0, 0><<<dim3(8, 4, 8), 256, 0, stream>>>(
      h1h, W2, nullptr, nullptr, part,
      1024, 2048, 2048, 2048, 1024, 256, 0, 0, 524288);
  ln_parts<<<512, 256, 0, stream>>>(part, 8, b2, x, xh, g3, be3);

  // ---- final projection: out = x @ W_vr^T + b_vr + tmpl  (XCD n-swizzle) ----
  glds6<true, 2, false, 2, 0><<<dim3(480, 1, 1), 256, 0, stream>>>(
      xh, Wvrh, b_vr, tmpl, out,
      15069, 1024, 1024, 1024, 15069, 0, 0, 0, 0);
}